// Round 2
// 331.156 us; speedup vs baseline: 1.1524x; 1.1524x over previous
//
#include <hip/hip_runtime.h>
#include <hip/hip_bf16.h>
#include <math.h>

#define H 8
#define D 128
#define HID 1024
#define KCONV 4

typedef __bf16 bhalf;
typedef __bf16 bhalf4 __attribute__((ext_vector_type(4)));
typedef __bf16 bhalf8 __attribute__((ext_vector_type(8)));
typedef float f32x4 __attribute__((ext_vector_type(4)));
typedef _Float16 hlf;
typedef _Float16 half8 __attribute__((ext_vector_type(8)));
typedef _Float16 half4v __attribute__((ext_vector_type(4)));

// ---- async global->LDS (direct-to-shared DMA, bypasses VGPRs) ----
__device__ __forceinline__ void async16(const void* g, void* l) {
    __builtin_amdgcn_global_load_lds(
        (const __attribute__((address_space(1))) void*)g,
        (__attribute__((address_space(3))) void*)l, 16, 0, 0);
}

// ---------------- bf16 MFMA GEMM: C[M,N] = A[M,K]*B[N,K]^T ----------------
// 128x64 tile, BK=32, 256 threads (4 waves, 2x2), global_load_lds staging.
// epi: 0 = fp32 store, 1 = eg transform, 2 = bf16 store,
//      3 = mega epilogue: c<3072 -> QKV fp32 (ldc 3072);
//          3072<=c<3328 -> XAG bf16 (ldc 256); 3328<=c<3336 -> BETA sigmoid
//          (ldc 8); c>=3336 -> discard (padding rows).
__global__ __launch_bounds__(256) void gemm_bf16_nt(const bhalf* A, const bhalf* B,
                                                    void* Cv,
                                                    int M, int N, int K,
                                                    int lda, int ldb, int ldc, int epi,
                                                    const float* __restrict__ A_log,
                                                    const float* __restrict__ dt_bias,
                                                    const bhalf* A2, const bhalf* B2,
                                                    void* C2, int epi2,
                                                    bhalf* __restrict__ pXAG,
                                                    float* __restrict__ pBETA)
{
    if (blockIdx.z) { A = A2; B = B2; Cv = C2; epi = epi2; }
    __shared__ __align__(16) bhalf As[128][32];   // 8 KB
    __shared__ __align__(16) bhalf Bs[64][32];    // 4 KB
    int tid = threadIdx.x;
    int wid = tid >> 6, lane = tid & 63;
    int rowBase = blockIdx.y * 128;
    int colBase = blockIdx.x * 64;
    int wm = wid >> 1, wn = wid & 1;

    f32x4 acc[4][2] = {};

    int r = lane >> 2;          // 16 rows per 1KB instr
    int cseg = lane & 3;        // 16B segment within 64B row

    for (int k0 = 0; k0 < K; k0 += 32) {
        __syncthreads();
#pragma unroll
        for (int s = 0; s < 3; ++s) {
            int j = wid * 3 + s;            // 12 instrs: 8 A + 4 B
            if (j < 8) {
                const bhalf* ga = A + (size_t)(rowBase + j * 16 + r) * lda + k0 + cseg * 8;
                async16(ga, &As[j * 16][0]);
            } else {
                int jb = j - 8;
                const bhalf* ga = B + (size_t)(colBase + jb * 16 + r) * ldb + k0 + cseg * 8;
                async16(ga, &Bs[jb * 16][0]);
            }
        }
        __syncthreads();
        int mq = lane & 15, kq = (lane >> 4) * 8;
        bhalf8 af[4], bfr[2];
#pragma unroll
        for (int mt = 0; mt < 4; ++mt)
            af[mt] = *(const bhalf8*)&As[wm * 64 + mt * 16 + mq][kq];
#pragma unroll
        for (int nt = 0; nt < 2; ++nt)
            bfr[nt] = *(const bhalf8*)&Bs[wn * 32 + nt * 16 + mq][kq];
#pragma unroll
        for (int mt = 0; mt < 4; ++mt)
#pragma unroll
            for (int nt = 0; nt < 2; ++nt)
                acc[mt][nt] = __builtin_amdgcn_mfma_f32_16x16x32_bf16(
                    af[mt], bfr[nt], acc[mt][nt], 0, 0, 0);
    }
    int rquad = (lane >> 4) * 4;
#pragma unroll
    for (int mt = 0; mt < 4; ++mt) {
        int m0 = rowBase + wm * 64 + mt * 16 + rquad;
#pragma unroll
        for (int nt = 0; nt < 2; ++nt) {
            int c = colBase + wn * 32 + (lane & 15) + nt * 16;
#pragma unroll
            for (int rr = 0; rr < 4; ++rr) {
                float val = acc[mt][nt][rr];
                int m = m0 + rr;
                if (epi == 0) {
                    ((float*)Cv)[(size_t)m * ldc + c] = val;
                } else if (epi == 1) {
                    int h = c >> 7, d = c & 127;
                    float z = val + dt_bias[h * D + d];
                    float sp = (z > 20.f) ? z : log1pf(expf(z));
                    ((float*)Cv)[(size_t)m * ldc + c] = expf(-expf(A_log[h]) * sp);
                } else if (epi == 2) {
                    ((bhalf*)Cv)[(size_t)m * ldc + c] = (bhalf)val;
                } else {
                    if (c < 3072) {
                        ((float*)Cv)[(size_t)m * 3072 + c] = val;
                    } else if (c < 3328) {
                        pXAG[(size_t)m * 256 + (c - 3072)] = (bhalf)val;
                    } else if (c < 3336) {
                        pBETA[(size_t)m * 8 + (c - 3328)] = 1.f / (1.f + expf(-val));
                    }
                }
            }
        }
    }
}

// ---------------- casts (vectorized, 4 elems/thread) ----------------
__global__ void cast1(const float* __restrict__ s, bhalf* __restrict__ d, int n4)
{
    int i = blockIdx.x * blockDim.x + threadIdx.x;
    if (i >= n4) return;
    float4 v = ((const float4*)s)[i];
    bhalf4 o = {(bhalf)v.x, (bhalf)v.y, (bhalf)v.z, (bhalf)v.w};
    ((bhalf4*)d)[i] = o;
}
__global__ void cast4(const float* __restrict__ s0, const float* __restrict__ s1,
                      const float* __restrict__ s2, const float* __restrict__ s3,
                      bhalf* __restrict__ d0, bhalf* __restrict__ d1,
                      bhalf* __restrict__ d2, bhalf* __restrict__ d3, int n4)
{
    int i = blockIdx.x * blockDim.x + threadIdx.x;
    if (i >= n4) return;
    int a = blockIdx.y;
    const float* s = (a == 0) ? s0 : (a == 1) ? s1 : (a == 2) ? s2 : s3;
    bhalf* d = (a == 0) ? d0 : (a == 1) ? d1 : (a == 2) ? d2 : d3;
    float4 v = ((const float4*)s)[i];
    bhalf4 o = {(bhalf)v.x, (bhalf)v.y, (bhalf)v.z, (bhalf)v.w};
    ((bhalf4*)d)[i] = o;
}

// ------- fused depthwise causal conv (K=4) + SiLU (+ rmsnorm*scale) --------
__global__ __launch_bounds__(128) void conv3_kernel(const float* __restrict__ QKV,
                                                    const float* __restrict__ wq,
                                                    const float* __restrict__ wk,
                                                    const float* __restrict__ wv,
                                                    float* __restrict__ Qc,
                                                    float* __restrict__ Kc,
                                                    float* __restrict__ Vc,
                                                    int T)
{
    int which = blockIdx.y;
    const float* w; float* out; int mode; float scale;
    if (which == 0)      { w = wq; out = Qc; mode = 1; scale = 1.0f / 128.0f; }
    else if (which == 1) { w = wk; out = Kc; mode = 1; scale = 0.08838834764831845f; }
    else                 { w = wv; out = Vc; mode = 0; scale = 1.f; }

    int bid = blockIdx.x;
    int h = bid % H;
    int t = (bid / H) % T;
    int b = bid / (H * T);
    int d = threadIdx.x;
    int c = h * D + d;
    const float* base = QKV + (size_t)b * T * 3072 + which * 1024 + c;
    float acc = 0.f;
#pragma unroll
    for (int j = 0; j < KCONV; ++j) {
        int tt = t - (KCONV - 1) + j;
        float xv = (tt >= 0) ? base[(size_t)tt * 3072] : 0.f;
        acc += xv * w[c * KCONV + j];
    }
    float y = acc / (1.f + expf(-acc));
    if (mode) {
        __shared__ float red[2];
        float ss = y * y;
#pragma unroll
        for (int s = 32; s > 0; s >>= 1) ss += __shfl_xor(ss, s, 64);
        if ((threadIdx.x & 63) == 0) red[threadIdx.x >> 6] = ss;
        __syncthreads();
        float tot = red[0] + red[1];
        float r = rsqrtf(tot * (1.f / D) + 1e-6f);
        y = y * r * scale;
    }
    out[(size_t)bid * D + d] = y;
}

// ---------------- DPP wave64 reduction ----------------
template <int CTRL>
__device__ __forceinline__ float dpp_add(float x) {
    int y = __builtin_amdgcn_update_dpp(0, __builtin_bit_cast(int, x),
                                        CTRL, 0xF, 0xF, false);
    return x + __builtin_bit_cast(float, y);
}
// after this chain the full-wave sum is valid in lane 63
__device__ __forceinline__ float wave_sum63(float x) {
    x = dpp_add<0x111>(x);   // row_shr:1
    x = dpp_add<0x112>(x);   // row_shr:2
    x = dpp_add<0x114>(x);   // row_shr:4
    x = dpp_add<0x118>(x);   // row_shr:8
    x = dpp_add<0x142>(x);   // row_bcast:15
    x = dpp_add<0x143>(x);   // row_bcast:31
    return x;
}

// =======================================================================
// Chunked gated-delta-rule (WY / UT-transform), chunk C = 32.
//
// Per chunk (local step i, decay e_t[d] = exp(g_t[d])):
//   A_i[d]   = prod_{s<=i} e_s            (inclusive, chunk-relative, <=1)
//   suff_i[d]= prod_{s>i} e_s             (<=1)
//   R_ij[d]  = prod_{j<s<=i} e_s          (<=1; computed iteratively)
//   P_ij  = sum_d k_i k_j R_ij  (i>j)       Ao_ij = sum_d q_i k_j R_ij (i>=j)
//   (I + diag(b) tril(P)) Delta = b*(V - Ktil S),  Ktil_i = k_i*A_i
//   W = M b Ktil, U = M b V  (M = inverse, folded via fwd substitution)
//   Delta = U - W S
//   O     = Qtil S + tril(Ao) Delta,      Qtil_i = q_i*A_i
//   S    <- diag(A_end) S + Kbar^T Delta, Kbar_i = k_i*suff_i
// All decay factors are products of e<=1: overflow-free, underflow->0 OK.
// =======================================================================

// ---- pass 1: fully parallel per (bh, chunk). fp32 compute, f16 out. ----
__global__ __launch_bounds__(256) void chunk_prep_kernel(
    const float* __restrict__ Q, const float* __restrict__ K,
    const float* __restrict__ V, const float* __restrict__ E,
    const float* __restrict__ BETA,
    hlf* __restrict__ Wn, float* __restrict__ Uf, hlf* __restrict__ Qt,
    hlf* __restrict__ AoL, hlf* __restrict__ KbT, float* __restrict__ Aend,
    int T)
{
    __shared__ __align__(16) float e_s[32][128];   // 16K
    __shared__ __align__(16) float k_s[32][128];   // 16K
    __shared__ __align__(16) float U_s[32][128];   // 16K
    __shared__ __align__(16) hlf  A_s[32][128];    // 8K
    __shared__ __align__(16) hlf  W_s[32][128];    // 8K
    __shared__ float P_s[32][32];                  // 4K (beta-folded L)
    __shared__ float Ao_s[32][32];                 // 4K
    __shared__ float beta_s[32];

    int tid = threadIdx.x, wid = tid >> 6, lane = tid & 63;
    int bid = blockIdx.x;
    int bh = bid >> 5, ch = bid & 31;
    int b = bh >> 3, h = bh & 7;
    int t0 = ch * 32;
    size_t rowb = (size_t)(b * T + t0) * 1024 + h * 128;
    size_t co = (size_t)bh * 32 + ch;

    // ---- stage e,k (32 rows x 512B each; 1 async16 covers 2 rows) ----
    int rs2 = lane >> 5, seg = (lane & 31) * 4;
#pragma unroll
    for (int p = wid * 4; p < wid * 4 + 4; ++p) {
        int row = p * 2 + rs2;
        async16(E + rowb + (size_t)row * 1024 + seg, &e_s[p * 2][0]);
        async16(K + rowb + (size_t)row * 1024 + seg, &k_s[p * 2][0]);
    }
    __syncthreads();

    // ---- phase 2: zero Ao, beta, cumulative products ----
    for (int x = tid; x < 1024; x += 256) Ao_s[x >> 5][x & 31] = 0.f;
    if (wid == 2 && lane < 32)
        beta_s[lane] = BETA[(size_t)(b * T + t0 + lane) * 8 + h];
    int d0 = lane * 2;
    if (wid == 0) {             // forward cumprod -> A_s, A_end
        float a0 = 1.f, a1 = 1.f;
        for (int t = 0; t < 32; ++t) {
            a0 *= e_s[t][d0]; a1 *= e_s[t][d0 + 1];
            A_s[t][d0] = (hlf)a0; A_s[t][d0 + 1] = (hlf)a1;
        }
        Aend[co * 128 + d0] = a0; Aend[co * 128 + d0 + 1] = a1;
    } else if (wid == 1) {      // backward suffix -> Kbar^T [d][t]
        float s0 = 1.f, s1 = 1.f;
        for (int t = 31; t >= 0; --t) {
            KbT[co * 4096 + (size_t)d0 * 32 + t]       = (hlf)(k_s[t][d0] * s0);
            KbT[co * 4096 + (size_t)(d0 + 1) * 32 + t] = (hlf)(k_s[t][d0 + 1] * s1);
            s0 *= e_s[t][d0]; s1 *= e_s[t][d0 + 1];
        }
    }
    __syncthreads();

    // ---- phase 3: P / Ao pairwise-decay triangle walk ----
#pragma unroll
    for (int ii = 0; ii < 8; ++ii) {
        int i = wid + ii * 4;
        float ki0 = k_s[i][d0], ki1 = k_s[i][d0 + 1];
        float2 qv = *(const float2*)(Q + rowb + (size_t)i * 1024 + d0);
        float aa = wave_sum63(qv.x * ki0 + qv.y * ki1);
        if (lane == 63) Ao_s[i][i] = aa;           // diag: R = 1
        float R0 = 1.f, R1 = 1.f;
        for (int j = i - 1; j >= 0; --j) {
            R0 *= e_s[j + 1][d0]; R1 *= e_s[j + 1][d0 + 1];
            float u0 = R0 * k_s[j][d0], u1 = R1 * k_s[j][d0 + 1];
            float pp = wave_sum63(ki0 * u0 + ki1 * u1);
            float a2 = wave_sum63(qv.x * u0 + qv.y * u1);
            if (lane == 63) { P_s[i][j] = pp; Ao_s[i][j] = a2; }
        }
    }
    __syncthreads();

    // ---- phase 4: fold beta into strict-lower L ----
    for (int x = tid; x < 1024; x += 256) {
        int i2 = x >> 5, j2 = x & 31;
        P_s[i2][j2] = (j2 < i2) ? P_s[i2][j2] * beta_s[i2] : 0.f;
    }
    __syncthreads();

    // ---- phase 5: (I+L)W = b*Ktil (wave0), (I+L)U = b*V (wave1), Qtil ----
    if (wid == 0) {
        for (int i = 0; i < 32; ++i) {
            float bb = beta_s[i];
            float a0 = bb * k_s[i][d0] * (float)A_s[i][d0];
            float a1 = bb * k_s[i][d0 + 1] * (float)A_s[i][d0 + 1];
            for (int k2 = 0; k2 < i; ++k2) {
                float L = P_s[i][k2];
                a0 -= L * (float)W_s[k2][d0];
                a1 -= L * (float)W_s[k2][d0 + 1];
            }
            W_s[i][d0] = (hlf)a0; W_s[i][d0 + 1] = (hlf)a1;
        }
    } else if (wid == 1) {
        for (int i = 0; i < 32; ++i) {
            float bb = beta_s[i];
            float2 vv = *(const float2*)(V + rowb + (size_t)i * 1024 + d0);
            float a0 = bb * vv.x, a1 = bb * vv.y;
            for (int k2 = 0; k2 < i; ++k2) {
                float L = P_s[i][k2];
                a0 -= L * U_s[k2][d0];
                a1 -= L * U_s[k2][d0 + 1];
            }
            U_s[i][d0] = a0; U_s[i][d0 + 1] = a1;
        }
    } else {
        for (int r2 = wid - 2; r2 < 32; r2 += 2) {
            float2 qv = *(const float2*)(Q + rowb + (size_t)r2 * 1024 + d0);
            Qt[co * 4096 + (size_t)r2 * 128 + d0]     = (hlf)(qv.x * (float)A_s[r2][d0]);
            Qt[co * 4096 + (size_t)r2 * 128 + d0 + 1] = (hlf)(qv.y * (float)A_s[r2][d0 + 1]);
        }
    }
    __syncthreads();

    // ---- phase 6: dumps ----
    for (int x = tid; x < 4096; x += 256) {
        Wn[co * 4096 + x] = (hlf)(-(float)W_s[x >> 7][x & 127]);
        Uf[co * 4096 + x] = U_s[x >> 7][x & 127];
    }
    for (int x = tid; x < 1024; x += 256)
        AoL[co * 1024 + x] = (hlf)Ao_s[x >> 5][x & 31];
}

// ---- pass 2: serial scan over 32 chunks; all heavy math on MFMA f16. ----
// grid = nbh*4 (bh-major: the 4 v-splits of one bh land on the same XCD).
__global__ __launch_bounds__(256) void chunk_scan_kernel(
    const hlf* __restrict__ Wn, const float* __restrict__ Uf,
    const hlf* __restrict__ Qt, const hlf* __restrict__ Ao,
    const hlf* __restrict__ KbT, const float* __restrict__ Aend,
    float* __restrict__ O, int T)
{
    __shared__ __align__(16) float Sf[32][132];   // S'[v][d] fp32 master
    __shared__ __align__(16) hlf  Sh[32][136];    // f16 copy for MFMA B-reads
    __shared__ __align__(16) hlf  Dt[32][40];     // Delta^T [v][j] f16
    __shared__ float Ae[128];

    int tid = threadIdx.x, wid = tid >> 6, lane = tid & 63;
    int nbh = gridDim.x >> 2;
    int bh = blockIdx.x % nbh, vs = blockIdx.x / nbh;
    int b = bh >> 3, h = bh & 7;
    int v0 = vs * 32;

    for (int r = wid; r < 32; r += 4) {
        for (int c2 = lane; c2 < 132; c2 += 64) Sf[r][c2] = 0.f;
        for (int c2 = lane; c2 < 136; c2 += 64) Sh[r][c2] = (hlf)0.f;
    }
    __syncthreads();

    int mq = lane & 15, kq = (lane >> 4) * 8, rq = (lane >> 4) * 4;
    int tr = (wid >> 1) * 16, vc = (wid & 1) * 16;     // Delta/O tile
    int vr2 = (wid >> 1) * 16, dh2 = (wid & 1) * 64;   // S-update tiles

    for (int c = 0; c < 32; ++c) {
        size_t co = (size_t)bh * 32 + c;
        const hlf*   Wc  = Wn  + co * 4096;
        const float* Uc  = Uf  + co * 4096;
        const hlf*   Qc2 = Qt  + co * 4096;
        const hlf*   Aoc = Ao  + co * 1024;
        const hlf*   Kbc = KbT + co * 4096;
        if (tid < 128) Ae[tid] = Aend[co * 128 + tid];

        // ---- Delta = U + (-W) @ S ----
        f32x4 dacc;
#pragma unroll
        for (int rr = 0; rr < 4; ++rr)
            dacc[rr] = Uc[(size_t)(tr + rq + rr) * 128 + v0 + vc + mq];
#pragma unroll
        for (int ks = 0; ks < 4; ++ks) {
            half8 aw = *(const half8*)&Wc[(size_t)(tr + mq) * 128 + ks * 32 + kq];
            half8 bs = *(const half8*)&Sh[vc + mq][ks * 32 + kq];
            dacc = __builtin_amdgcn_mfma_f32_16x16x32_f16(aw, bs, dacc, 0, 0, 0);
        }
        half4v dh4;
#pragma unroll
        for (int rr = 0; rr < 4; ++rr) dh4[rr] = (hlf)dacc[rr];
        *(half4v*)&Dt[vc + mq][tr + rq] = dh4;
        __syncthreads();

        // ---- O = Qtil @ S + Ao @ Delta ----
        f32x4 oacc = {0.f, 0.f, 0.f, 0.f};
#pragma unroll
        for (int ks = 0; ks < 4; ++ks) {
            half8 aq = *(const half8*)&Qc2[(size_t)(tr + mq) * 128 + ks * 32 + kq];
            half8 bs = *(const half8*)&Sh[vc + mq][ks * 32 + kq];
            oacc = __builtin_amdgcn_mfma_f32_16x16x32_f16(aq, bs, oacc, 0, 0, 0);
        }
        {
            half8 aA = *(const half8*)&Aoc[(tr + mq) * 32 + kq];
            half8 bD = *(const half8*)&Dt[vc + mq][kq];
            oacc = __builtin_amdgcn_mfma_f32_16x16x32_f16(aA, bD, oacc, 0, 0, 0);
        }
#pragma unroll
        for (int rr = 0; rr < 4; ++rr)
            O[((size_t)(b * T + c * 32 + tr + rq + rr) * 8 + h) * 128 + v0 + vc + mq]
                = oacc[rr];

        // ---- S' = diag(Aend)*S' + Delta^T @ Kbar ----
        f32x4 sacc[4];
        half8 aD = *(const half8*)&Dt[vr2 + mq][kq];
#pragma unroll
        for (int nt = 0; nt < 4; ++nt) {
            int dc = dh2 + nt * 16 + mq;
#pragma unroll
            for (int rr = 0; rr < 4; ++rr)
                sacc[nt][rr] = Sf[vr2 + rq + rr][dc] * Ae[dc];
            half8 bK = *(const half8*)&Kbc[(size_t)dc * 32 + kq];
            sacc[nt] = __builtin_amdgcn_mfma_f32_16x16x32_f16(aD, bK, sacc[nt], 0, 0, 0);
        }
        __syncthreads();
#pragma unroll
        for (int nt = 0; nt < 4; ++nt) {
            int dc = dh2 + nt * 16 + mq;
#pragma unroll
            for (int rr = 0; rr < 4; ++rr) {
                Sf[vr2 + rq + rr][dc] = sacc[nt][rr];
                Sh[vr2 + rq + rr][dc] = (hlf)sacc[nt][rr];
            }
        }
        __syncthreads();
    }
}

// -------- out = rmsnorm(o)*w*sigmoid(gate) -> bf16 (for final MFMA GEMM) ----
__global__ __launch_bounds__(128) void outnorm_kernel(const float* __restrict__ O,
                                                      const float* __restrict__ GATE,
                                                      const float* __restrict__ w,
                                                      bhalf* __restrict__ Obf)
{
    int bid = blockIdx.x;
    int d = threadIdx.x;
    size_t base = (size_t)bid * D;
    float y = O[base + d];
    __shared__ float red[2];
    float ss = y * y;
#pragma unroll
    for (int s = 32; s > 0; s >>= 1) ss += __shfl_xor(ss, s, 64);
    if ((threadIdx.x & 63) == 0) red[threadIdx.x >> 6] = ss;
    __syncthreads();
    float tot = red[0] + red[1];
    float r = rsqrtf(tot * (1.f / D) + 1e-5f);
    float gz = GATE[base + d];
    float sg = 1.f / (1.f + expf(-gz));
    Obf[base + d] = (bhalf)(y * r * w[d] * sg);
}

extern "C" void kernel_launch(void* const* d_in, const int* in_sizes, int n_in,
                              void* d_out, int out_size, void* d_ws, size_t ws_size,
                              hipStream_t stream)
{
    const float* x       = (const float*)d_in[0];
    const float* Wq      = (const float*)d_in[1];
    const float* Wk      = (const float*)d_in[2];
    const float* Wv      = (const float*)d_in[3];
    const float* wq_conv = (const float*)d_in[4];
    const float* wk_conv = (const float*)d_in[5];
    const float* wv_conv = (const float*)d_in[6];
    const float* Wfa     = (const float*)d_in[7];
    const float* Wfb     = (const float*)d_in[8];
    const float* Wb      = (const float*)d_in[9];
    const float* Wga     = (const float*)d_in[10];
    const float* Wgb     = (const float*)d_in[11];
    const float* A_log   = (const float*)d_in[12];
    const float* dt_bias = (const float*)d_in[13];
    const float* o_norm_w= (const float*)d_in[14];
    const float* Wo      = (const float*)d_in[15];

    int BT = in_sizes[0] / HID;     // B*T
    int T = 1024;
    int B_ = BT / T;
    size_t M = (size_t)BT;
    size_t sz_big = M * HID;
    const int nW = HID * HID;       // 1M
    const int nS = D * HID;         // 131072
    const int NCAT = 3392;          // 3072 qkv | 256 fa/ga | 8 beta | 56 pad

    // ---- explicit workspace layout (no aliasing) ----
    float* fp = (float*)d_ws;
    float* QKVp = fp;               fp += 3 * sz_big;   // M x 3072 fused q|k|v
    float* Qc   = fp;               fp += sz_big;
    float* Kc   = fp;               fp += sz_big;
    float* Vc   = fp;               fp += sz_big;
    float* EGb  = fp;               fp += sz_big;
    float* GATE = fp;               fp += sz_big;
    float* Obuf = fp;               fp += sz_big;
    float* BETA = fp;               fp += M * H;
    bhalf* bp = (bhalf*)fp;
    bhalf* xb   = bp;               bp += sz_big;
    bhalf* Wcat = bp;               bp += (size_t)NCAT * HID;  // Wq|Wk|Wv|Wfa|Wga|Wb|pad
    bhalf* Wob  = bp;               bp += nW;
    bhalf* Wfbb = bp;               bp += nS;
    bhalf* Wgbb = bp;               bp += nS;
    bhalf* XAG  = bp;               bp += M * 256;          // M x 256: xa|xg
    bhalf* Obf  = bp;               bp += sz_big;

    dim3 blk(256);

    // casts (4 launches, vectorized x4)
    cast1<<<(int)((sz_big / 4 + 255) / 256), 256, 0, stream>>>(x, xb, (int)(sz_big / 4));
    cast4<<<dim3((nW / 4 + 255) / 256, 4), 256, 0, stream>>>(Wq, Wk, Wv, Wo,
        Wcat, Wcat + nW, Wcat + 2 * (size_t)nW, Wob, nW / 4);
    cast4<<<dim3((nS / 4 + 255) / 256, 4), 256, 0, stream>>>(Wfa, Wga, Wfb, Wgb,
        Wcat + 3 * (size_t)nW, Wcat + 3 * (size_t)nW + nS, Wfbb, Wgbb, nS / 4);
    cast1<<<(H * HID / 4 + 255) / 256, 256, 0, stream>>>(Wb,
        Wcat + 3 * (size_t)nW + 2 * (size_t)nS, H * HID / 4);

    // mega first-stage GEMM: [QKV | XA,XG | beta] = xb @ Wcat^T  (N=3392)
    gemm_bf16_nt<<<dim3(NCAT / 64, BT / 128), blk, 0, stream>>>(
        xb, Wcat, QKVp, BT, NCAT, HID, HID, HID, 3072, 3, nullptr, nullptr,
        nullptr, nullptr, nullptr, 0, XAG, BETA);

    // conv + silu (+norm) fused, one launch
    conv3_kernel<<<dim3(BT * H, 3), 128, 0, stream>>>(QKVp,
                                                      wq_conv, wk_conv, wv_conv,
                                                      Qc, Kc, Vc, T);

    // second stage batched (z=0: EGb w/ fused eg transform; z=1: GATE)
    gemm_bf16_nt<<<dim3(HID / 64, BT / 128, 2), blk, 0, stream>>>(
        XAG, Wfbb, EGb, BT, HID, D, 256, D, HID, 1, A_log, dt_bias,
        XAG + D, Wgbb, GATE, 0, nullptr, nullptr);

    // ---- chunked recurrence: QKVp (24MB) is dead after conv3; reuse it ----
    int nbh = B_ * 8;
    float* Uf   = QKVp;
    float* Aend = Uf + (size_t)nbh * 32 * 4096;
    hlf* Wn  = (hlf*)(Aend + (size_t)nbh * 32 * 128);
    hlf* Qt  = Wn  + (size_t)nbh * 32 * 4096;
    hlf* AoLp= Qt  + (size_t)nbh * 32 * 4096;
    hlf* KbT = AoLp + (size_t)nbh * 32 * 1024;

    chunk_prep_kernel<<<nbh * 32, 256, 0, stream>>>(Qc, Kc, Vc, EGb, BETA,
                                                    Wn, Uf, Qt, AoLp, KbT, Aend, T);
    chunk_scan_kernel<<<nbh * 4, 256, 0, stream>>>(Wn, Uf, Qt, AoLp, KbT, Aend,
                                                   Obuf, T);

    // output norm * gate -> bf16
    outnorm_kernel<<<BT * H, 128, 0, stream>>>(Obuf, GATE, o_norm_w, Obf);

    // final projection (bf16 MFMA)
    gemm_bf16_nt<<<dim3(HID / 64, BT / 128), blk, 0, stream>>>(
        Obf, Wob, (float*)d_out, BT, HID, HID, HID, HID, HID, 0, nullptr, nullptr,
        nullptr, nullptr, nullptr, 0, nullptr, nullptr);
}